// Round 1
// baseline (104.180 us; speedup 1.0000x reference)
//
#include <hip/hip_runtime.h>

// HierarchicalMultinomialRegression: fused fixed-effects GEMV + per-row AR(1)
// recurrence replay + gather. Never materializes u (B,L,T,Km1).
//
// Inputs (setup_inputs dict order):
//  0: X         (N, 64)        f32
//  1: beta      (64, 7)        f32
//  2: raw_rho   (7, 7)         f32   (L, Km1)
//  3: raw_chol  (7, 7, 7)      f32   (Km1, L, L), lower-tri
//  4: eps       (B, 7, 20, 7)  f32   (B, L, T, Km1)
//  5: batter_ids (N,) i32
//  6: league_ids (N,) i32
//  7: season_ids (N,) i32
// Output: logits (N,8) then eps_sample (N,7), concatenated flat, f32.

#define NF 64
#define LDIM 7
#define TDIM 20
#define KM1 7

__global__ __launch_bounds__(256) void hmr_kernel(
    const float* __restrict__ X,
    const float* __restrict__ beta,
    const float* __restrict__ raw_rho,
    const float* __restrict__ raw_chol,
    const float* __restrict__ eps,
    const int* __restrict__ batter_ids,
    const int* __restrict__ league_ids,
    const int* __restrict__ season_ids,
    float* __restrict__ out,
    int n_total)
{
    // LDS-staged small constants
    __shared__ float s_beta[NF * KM1];      // beta[j][k], broadcast access
    __shared__ float s_rho[LDIM][KM1];      // tanh(raw_rho)
    __shared__ float s_sd[LDIM][KM1];       // scaling[l][k] * chol[k][l][l]
    __shared__ float s_M[KM1][LDIM];        // M[k][j] = sum_i chol[k][i][j]

    const int tid = threadIdx.x;

    for (int i = tid; i < NF * KM1; i += blockDim.x) s_beta[i] = beta[i];

    if (tid < LDIM * KM1) {
        const int l = tid / KM1, k = tid % KM1;
        const float r = tanhf(raw_rho[l * KM1 + k]);
        s_rho[l][k] = r;
        const float scal = 1.0f / sqrtf(1.0f - r * r);
        s_sd[l][k] = scal * raw_chol[k * (LDIM * LDIM) + l * LDIM + l];
        // reuse tid as (k2, j) pair for M
        const int k2 = l, j = k;  // same 7x7 index space
        float m = 0.f;
        #pragma unroll
        for (int i = 0; i < LDIM; ++i)
            m += raw_chol[k2 * (LDIM * LDIM) + i * LDIM + j];
        s_M[k2][j] = m;
    }
    __syncthreads();

    const int n = blockIdx.x * blockDim.x + tid;
    if (n >= n_total) return;

    const int b = batter_ids[n];
    const int l = league_ids[n];
    const int t = season_ids[n];

    // ---- fixed effects: acc[k] = sum_j X[n,j] * beta[j,k] ----
    float acc[KM1];
    #pragma unroll
    for (int k = 0; k < KM1; ++k) acc[k] = 0.f;

    const float4* __restrict__ xrow = reinterpret_cast<const float4*>(X + (long)n * NF);
    #pragma unroll
    for (int j4 = 0; j4 < NF / 4; ++j4) {
        const float4 x = xrow[j4];
        const float* b0 = &s_beta[(j4 * 4 + 0) * KM1];
        const float* b1 = &s_beta[(j4 * 4 + 1) * KM1];
        const float* b2 = &s_beta[(j4 * 4 + 2) * KM1];
        const float* b3 = &s_beta[(j4 * 4 + 3) * KM1];
        #pragma unroll
        for (int k = 0; k < KM1; ++k)
            acc[k] += x.x * b0[k] + x.y * b1[k] + x.z * b2[k] + x.w * b3[k];
    }

    // ---- AR(1) recurrence replay up to t ----
    const float* __restrict__ erow = eps + ((long)b * LDIM + l) * (TDIM * KM1);

    float u[KM1];
    #pragma unroll
    for (int k = 0; k < KM1; ++k) u[k] = s_sd[l][k] * erow[k];

    for (int s = 1; s <= t; ++s) {
        float e[KM1];
        #pragma unroll
        for (int k = 0; k < KM1; ++k) e[k] = erow[s * KM1 + k];
        float nz[KM1];
        #pragma unroll
        for (int j = 0; j < KM1; ++j) {
            float m = 0.f;
            #pragma unroll
            for (int k = 0; k < KM1; ++k) m += e[k] * s_M[k][j];
            nz[j] = m;
        }
        #pragma unroll
        for (int j = 0; j < KM1; ++j)
            u[j] = s_rho[l][j] * u[j] + nz[j];
    }

    // ---- outputs ----
    float* lg = out + (long)n * 8;
    lg[0] = 0.f;
    #pragma unroll
    for (int k = 0; k < KM1; ++k) lg[1 + k] = acc[k] + u[k];

    float* es = out + (long)n_total * 8 + (long)n * KM1;
    #pragma unroll
    for (int k = 0; k < KM1; ++k) es[k] = erow[t * KM1 + k];
}

extern "C" void kernel_launch(void* const* d_in, const int* in_sizes, int n_in,
                              void* d_out, int out_size, void* d_ws, size_t ws_size,
                              hipStream_t stream)
{
    const float* X        = (const float*)d_in[0];
    const float* beta     = (const float*)d_in[1];
    const float* raw_rho  = (const float*)d_in[2];
    const float* raw_chol = (const float*)d_in[3];
    const float* eps      = (const float*)d_in[4];
    const int* batter_ids = (const int*)d_in[5];
    const int* league_ids = (const int*)d_in[6];
    const int* season_ids = (const int*)d_in[7];
    float* out = (float*)d_out;

    const int n_total = in_sizes[5];  // N = 200000
    const int block = 256;
    const int grid = (n_total + block - 1) / block;

    hmr_kernel<<<grid, block, 0, stream>>>(X, beta, raw_rho, raw_chol, eps,
                                           batter_ids, league_ids, season_ids,
                                           out, n_total);
}